// Round 1
// baseline (412.518 us; speedup 1.0000x reference)
//
#include <hip/hip_runtime.h>

#define B_SZ   512
#define VFD    4096
#define HIDD   2048
#define EMBD   300
#define NLAB   2000

// ---------------------------------------------------------------------------
// GEMM1: H[512,2048] = relu(X[512,4096]) @ W1[4096,2048] + b1
// BM=64 BN=64 BK=32, 256 threads, 4x4 per thread, register-prefetch staging.
// ---------------------------------------------------------------------------
__global__ __launch_bounds__(256) void gemm1_kernel(
    const float* __restrict__ X, const float* __restrict__ W1,
    const float* __restrict__ b1, float* __restrict__ H)
{
    __shared__ float As[32][68];   // [k][m], padded (stride 68 keeps 16B align, breaks bank collisions)
    __shared__ float Bs[32][68];   // [k][n]

    const int tid = threadIdx.x;
    const int tx  = tid & 15;      // col group
    const int ty  = tid >> 4;      // row group
    const int m0  = blockIdx.y * 64;
    const int n0  = blockIdx.x * 64;

    // staging slot assignment (2 float4 per thread per matrix)
    const int arow0 = tid >> 3,        akq0 = tid & 7;       // A slot i=0
    const int arow1 = (tid >> 3) + 32, akq1 = tid & 7;       // A slot i=1
    const int bkr0  = tid >> 4,        bcq  = tid & 15;      // B slot i=0
    const int bkr1  = (tid >> 4) + 16;                       // B slot i=1

    float acc[4][4] = {};
    float4 pa0, pa1, pb0, pb1;

    // prefetch tile 0
    pa0 = *(const float4*)&X[(m0 + arow0) * VFD + akq0 * 4];
    pa1 = *(const float4*)&X[(m0 + arow1) * VFD + akq1 * 4];
    pb0 = *(const float4*)&W1[(bkr0) * HIDD + n0 + bcq * 4];
    pb1 = *(const float4*)&W1[(bkr1) * HIDD + n0 + bcq * 4];

    const int ntiles = VFD / 32;
    for (int t = 0; t < ntiles; ++t) {
        // regs -> LDS (relu applied to A here)
        {
            float4 a = pa0;
            As[akq0*4+0][arow0] = fmaxf(a.x, 0.f);
            As[akq0*4+1][arow0] = fmaxf(a.y, 0.f);
            As[akq0*4+2][arow0] = fmaxf(a.z, 0.f);
            As[akq0*4+3][arow0] = fmaxf(a.w, 0.f);
            a = pa1;
            As[akq1*4+0][arow1] = fmaxf(a.x, 0.f);
            As[akq1*4+1][arow1] = fmaxf(a.y, 0.f);
            As[akq1*4+2][arow1] = fmaxf(a.z, 0.f);
            As[akq1*4+3][arow1] = fmaxf(a.w, 0.f);
            *(float4*)&Bs[bkr0][bcq*4] = pb0;
            *(float4*)&Bs[bkr1][bcq*4] = pb1;
        }
        __syncthreads();

        // prefetch next tile (loads fly during compute below)
        if (t + 1 < ntiles) {
            const int k0 = (t + 1) * 32;
            pa0 = *(const float4*)&X[(m0 + arow0) * VFD + k0 + akq0 * 4];
            pa1 = *(const float4*)&X[(m0 + arow1) * VFD + k0 + akq1 * 4];
            pb0 = *(const float4*)&W1[(k0 + bkr0) * HIDD + n0 + bcq * 4];
            pb1 = *(const float4*)&W1[(k0 + bkr1) * HIDD + n0 + bcq * 4];
        }

        // compute 32 k-steps, 4x4 per thread
        #pragma unroll 8
        for (int k = 0; k < 32; ++k) {
            float4 a4 = *(float4*)&As[k][ty * 4];
            float4 b4 = *(float4*)&Bs[k][tx * 4];
            float av[4] = {a4.x, a4.y, a4.z, a4.w};
            float bv[4] = {b4.x, b4.y, b4.z, b4.w};
            #pragma unroll
            for (int i = 0; i < 4; ++i)
                #pragma unroll
                for (int j = 0; j < 4; ++j)
                    acc[i][j] += av[i] * bv[j];
        }
        __syncthreads();
    }

    // epilogue: + b1, store
    const float4 bias = *(const float4*)&b1[n0 + tx * 4];
    #pragma unroll
    for (int i = 0; i < 4; ++i) {
        const int row = m0 + ty * 4 + i;
        float4 o;
        o.x = acc[i][0] + bias.x;
        o.y = acc[i][1] + bias.y;
        o.z = acc[i][2] + bias.z;
        o.w = acc[i][3] + bias.w;
        *(float4*)&H[row * HIDD + n0 + tx * 4] = o;
    }
}

// ---------------------------------------------------------------------------
// GEMM2: E[512,300] = relu(H[512,2048]) @ W2[2048,300] + b2
// BM=16 BN=64 BK=32, 256 threads, 1x4 per thread.
// ---------------------------------------------------------------------------
__global__ __launch_bounds__(256) void gemm2_kernel(
    const float* __restrict__ H, const float* __restrict__ W2,
    const float* __restrict__ b2, float* __restrict__ E)
{
    __shared__ float As[32][17];   // [k][m]
    __shared__ float Bs[32][68];   // [k][n]

    const int tid = threadIdx.x;
    const int tx  = tid & 15;
    const int ty  = tid >> 4;
    const int n0  = blockIdx.x * 64;
    const int m0  = blockIdx.y * 16;

    // A staging: 16 rows x 8 kq float4 slots = 128 (threads < 128)
    const int valid_a = (tid < 128);
    const int ar  = tid >> 3, akq = tid & 7;
    // B staging: 32 k x 16 cq slots = 512 -> 2 per thread
    const int bkr0 = tid >> 4, bkr1 = (tid >> 4) + 16, bcq = tid & 15;
    const int bcol = n0 + bcq * 4;
    const bool colok = (bcol < EMBD);

    float acc[4] = {};
    float4 pa = {0,0,0,0}, pb0 = {0,0,0,0}, pb1 = {0,0,0,0};

    if (valid_a) pa = *(const float4*)&H[(m0 + ar) * HIDD + akq * 4];
    if (colok) {
        pb0 = *(const float4*)&W2[(bkr0) * EMBD + bcol];
        pb1 = *(const float4*)&W2[(bkr1) * EMBD + bcol];
    }

    const int ntiles = HIDD / 32;
    for (int t = 0; t < ntiles; ++t) {
        if (valid_a) {
            As[akq*4+0][ar] = fmaxf(pa.x, 0.f);
            As[akq*4+1][ar] = fmaxf(pa.y, 0.f);
            As[akq*4+2][ar] = fmaxf(pa.z, 0.f);
            As[akq*4+3][ar] = fmaxf(pa.w, 0.f);
        }
        *(float4*)&Bs[bkr0][bcq*4] = pb0;
        *(float4*)&Bs[bkr1][bcq*4] = pb1;
        __syncthreads();

        if (t + 1 < ntiles) {
            const int k0 = (t + 1) * 32;
            if (valid_a) pa = *(const float4*)&H[(m0 + ar) * HIDD + k0 + akq * 4];
            if (colok) {
                pb0 = *(const float4*)&W2[(k0 + bkr0) * EMBD + bcol];
                pb1 = *(const float4*)&W2[(k0 + bkr1) * EMBD + bcol];
            }
        }

        #pragma unroll 8
        for (int k = 0; k < 32; ++k) {
            const float a = As[k][ty];
            float4 b4 = *(float4*)&Bs[k][tx * 4];
            acc[0] += a * b4.x;
            acc[1] += a * b4.y;
            acc[2] += a * b4.z;
            acc[3] += a * b4.w;
        }
        __syncthreads();
    }

    const int col = n0 + tx * 4;
    if (col < EMBD) {
        const float4 bias = *(const float4*)&b2[col];
        float4 o;
        o.x = acc[0] + bias.x;
        o.y = acc[1] + bias.y;
        o.z = acc[2] + bias.z;
        o.w = acc[3] + bias.w;
        *(float4*)&E[(m0 + ty) * EMBD + col] = o;
    }
}

// ---------------------------------------------------------------------------
// Scores: out[b,n] = -sum_d relu(E[b,d] - G[n,d])^2
// Tile: 32 batch x 64 labels per block, D staged in chunks of 64 (zero-padded).
// 256 threads: each thread 2 rows x 4 labels.
// ---------------------------------------------------------------------------
__global__ __launch_bounds__(256) void scores_kernel(
    const float* __restrict__ E, const float* __restrict__ G,
    float* __restrict__ out)
{
    __shared__ float Es[32][68];
    __shared__ float Gs[64][68];

    const int tid = threadIdx.x;
    const int tx  = tid & 15;
    const int ty  = tid >> 4;
    const int n0  = blockIdx.x * 64;
    const int b0  = blockIdx.y * 32;

    float acc[2][4] = {};

    for (int dc = 0; dc < 320; dc += 64) {
        // stage E: 32 rows x 16 q slots = 512 -> 2 per thread
        #pragma unroll
        for (int i = 0; i < 2; ++i) {
            const int s = tid + 256 * i;
            const int row = s >> 4, q = s & 15;
            const int d = dc + q * 4;
            float4 v = {0,0,0,0};
            if (d < EMBD) v = *(const float4*)&E[(b0 + row) * EMBD + d];
            *(float4*)&Es[row][q * 4] = v;
        }
        // stage G: 64 rows x 16 q slots = 1024 -> 4 per thread
        #pragma unroll
        for (int i = 0; i < 4; ++i) {
            const int s = tid + 256 * i;
            const int row = s >> 4, q = s & 15;
            const int n = n0 + row;
            const int d = dc + q * 4;
            float4 v = {0,0,0,0};
            if (n < NLAB && d < EMBD) v = *(const float4*)&G[n * EMBD + d];
            *(float4*)&Gs[row][q * 4] = v;
        }
        __syncthreads();

        #pragma unroll 4
        for (int d = 0; d < 64; d += 4) {
            float4 e0 = *(float4*)&Es[ty * 2 + 0][d];
            float4 e1 = *(float4*)&Es[ty * 2 + 1][d];
            float ev[2][4] = {{e0.x, e0.y, e0.z, e0.w}, {e1.x, e1.y, e1.z, e1.w}};
            #pragma unroll
            for (int r = 0; r < 4; ++r) {
                float4 g4 = *(float4*)&Gs[tx + 16 * r][d];
                float gv[4] = {g4.x, g4.y, g4.z, g4.w};
                #pragma unroll
                for (int p = 0; p < 2; ++p) {
                    #pragma unroll
                    for (int c = 0; c < 4; ++c) {
                        float diff = fmaxf(ev[p][c] - gv[c], 0.f);
                        acc[p][r] += diff * diff;
                    }
                }
            }
        }
        __syncthreads();
    }

    #pragma unroll
    for (int p = 0; p < 2; ++p) {
        const int b = b0 + ty * 2 + p;
        #pragma unroll
        for (int r = 0; r < 4; ++r) {
            const int n = n0 + tx + 16 * r;
            if (n < NLAB) out[b * NLAB + n] = -acc[p][r];
        }
    }
}

// ---------------------------------------------------------------------------
extern "C" void kernel_launch(void* const* d_in, const int* in_sizes, int n_in,
                              void* d_out, int out_size, void* d_ws, size_t ws_size,
                              hipStream_t stream)
{
    const float* vfs = (const float*)d_in[0];   // [512,4096]
    const float* W1  = (const float*)d_in[1];   // [4096,2048]
    const float* b1  = (const float*)d_in[2];   // [2048]
    const float* W2  = (const float*)d_in[3];   // [2048,300]
    const float* b2  = (const float*)d_in[4];   // [300]
    const float* G   = (const float*)d_in[5];   // [2000,300]

    float* out    = (float*)d_out;
    float* scores = out;                        // [512*2000]
    float* E      = out + (size_t)B_SZ * NLAB;  // [512*300]
    float* H      = (float*)d_ws;               // [512*2048] scratch

    gemm1_kernel<<<dim3(HIDD / 64, B_SZ / 64), 256, 0, stream>>>(vfs, W1, b1, H);
    gemm2_kernel<<<dim3((EMBD + 63) / 64, B_SZ / 16), 256, 0, stream>>>(H, W2, b2, E);
    scores_kernel<<<dim3((NLAB + 63) / 64, B_SZ / 32), 256, 0, stream>>>(E, G, scores);
}

// Round 2
// 285.808 us; speedup vs baseline: 1.4433x; 1.4433x over previous
//
#include <hip/hip_runtime.h>

#define B_SZ   512
#define VFD    4096
#define HIDD   2048
#define EMBD   300
#define NLAB   2000

#define G1_SPLIT 4          // k-chunks for gemm1 (K=4096 -> 1024 each)
#define G2_SPLIT 8          // k-chunks for gemm2 (K=2048 -> 256 each)

// ---------------------------------------------------------------------------
// GEMM1 (split-K): H[512,2048] += relu(X[512,4096]) @ W1[4096,2048] (+ b1 on chunk 0)
// BM=64 BN=64 BK=32, 256 threads, 4x4 per thread, register-prefetch staging.
// Grid (32, 8, G1_SPLIT); H must be zeroed before launch.
// ---------------------------------------------------------------------------
__global__ __launch_bounds__(256) void gemm1_kernel(
    const float* __restrict__ X, const float* __restrict__ W1,
    const float* __restrict__ b1, float* __restrict__ H)
{
    __shared__ float As[32][68];   // [k][m]
    __shared__ float Bs[32][68];   // [k][n]

    const int tid = threadIdx.x;
    const int tx  = tid & 15;
    const int ty  = tid >> 4;
    const int m0  = blockIdx.y * 64;
    const int n0  = blockIdx.x * 64;
    const int kbase = blockIdx.z * (VFD / G1_SPLIT);

    const int arow0 = tid >> 3,        akq0 = tid & 7;
    const int arow1 = (tid >> 3) + 32, akq1 = tid & 7;
    const int bkr0  = tid >> 4,        bcq  = tid & 15;
    const int bkr1  = (tid >> 4) + 16;

    float acc[4][4] = {};
    float4 pa0, pa1, pb0, pb1;

    // prefetch tile 0 of this k-chunk
    pa0 = *(const float4*)&X[(m0 + arow0) * VFD + kbase + akq0 * 4];
    pa1 = *(const float4*)&X[(m0 + arow1) * VFD + kbase + akq1 * 4];
    pb0 = *(const float4*)&W1[(kbase + bkr0) * HIDD + n0 + bcq * 4];
    pb1 = *(const float4*)&W1[(kbase + bkr1) * HIDD + n0 + bcq * 4];

    const int ntiles = (VFD / G1_SPLIT) / 32;   // 32
    for (int t = 0; t < ntiles; ++t) {
        {
            float4 a = pa0;
            As[akq0*4+0][arow0] = fmaxf(a.x, 0.f);
            As[akq0*4+1][arow0] = fmaxf(a.y, 0.f);
            As[akq0*4+2][arow0] = fmaxf(a.z, 0.f);
            As[akq0*4+3][arow0] = fmaxf(a.w, 0.f);
            a = pa1;
            As[akq1*4+0][arow1] = fmaxf(a.x, 0.f);
            As[akq1*4+1][arow1] = fmaxf(a.y, 0.f);
            As[akq1*4+2][arow1] = fmaxf(a.z, 0.f);
            As[akq1*4+3][arow1] = fmaxf(a.w, 0.f);
            *(float4*)&Bs[bkr0][bcq*4] = pb0;
            *(float4*)&Bs[bkr1][bcq*4] = pb1;
        }
        __syncthreads();

        if (t + 1 < ntiles) {
            const int k0 = kbase + (t + 1) * 32;
            pa0 = *(const float4*)&X[(m0 + arow0) * VFD + k0 + akq0 * 4];
            pa1 = *(const float4*)&X[(m0 + arow1) * VFD + k0 + akq1 * 4];
            pb0 = *(const float4*)&W1[(k0 + bkr0) * HIDD + n0 + bcq * 4];
            pb1 = *(const float4*)&W1[(k0 + bkr1) * HIDD + n0 + bcq * 4];
        }

        #pragma unroll 8
        for (int k = 0; k < 32; ++k) {
            float4 a4 = *(float4*)&As[k][ty * 4];
            float4 b4 = *(float4*)&Bs[k][tx * 4];
            float av[4] = {a4.x, a4.y, a4.z, a4.w};
            float bv[4] = {b4.x, b4.y, b4.z, b4.w};
            #pragma unroll
            for (int i = 0; i < 4; ++i)
                #pragma unroll
                for (int j = 0; j < 4; ++j)
                    acc[i][j] += av[i] * bv[j];
        }
        __syncthreads();
    }

    // epilogue: chunk 0 contributes bias; everyone atomically accumulates
    float4 bias = {0.f, 0.f, 0.f, 0.f};
    if (blockIdx.z == 0) bias = *(const float4*)&b1[n0 + tx * 4];
    #pragma unroll
    for (int i = 0; i < 4; ++i) {
        float* row = &H[(size_t)(m0 + ty * 4 + i) * HIDD + n0 + tx * 4];
        atomicAdd(row + 0, acc[i][0] + bias.x);
        atomicAdd(row + 1, acc[i][1] + bias.y);
        atomicAdd(row + 2, acc[i][2] + bias.z);
        atomicAdd(row + 3, acc[i][3] + bias.w);
    }
}

// ---------------------------------------------------------------------------
// GEMM2 (split-K): E[512,300] += relu(H) @ W2[2048,300] (+ b2 on chunk 0)
// BM=16 BN=64 BK=32, 256 threads, 1x4 per thread. Grid (5, 32, G2_SPLIT).
// E must be zeroed before launch.
// ---------------------------------------------------------------------------
__global__ __launch_bounds__(256) void gemm2_kernel(
    const float* __restrict__ H, const float* __restrict__ W2,
    const float* __restrict__ b2, float* __restrict__ E)
{
    __shared__ float As[32][17];
    __shared__ float Bs[32][68];

    const int tid = threadIdx.x;
    const int tx  = tid & 15;
    const int ty  = tid >> 4;
    const int n0  = blockIdx.x * 64;
    const int m0  = blockIdx.y * 16;
    const int kbase = blockIdx.z * (HIDD / G2_SPLIT);

    const int valid_a = (tid < 128);
    const int ar  = tid >> 3, akq = tid & 7;
    const int bkr0 = tid >> 4, bkr1 = (tid >> 4) + 16, bcq = tid & 15;
    const int bcol = n0 + bcq * 4;
    const bool colok = (bcol < EMBD);

    float acc[4] = {};
    float4 pa = {0,0,0,0}, pb0 = {0,0,0,0}, pb1 = {0,0,0,0};

    if (valid_a) pa = *(const float4*)&H[(m0 + ar) * HIDD + kbase + akq * 4];
    if (colok) {
        pb0 = *(const float4*)&W2[(kbase + bkr0) * EMBD + bcol];
        pb1 = *(const float4*)&W2[(kbase + bkr1) * EMBD + bcol];
    }

    const int ntiles = (HIDD / G2_SPLIT) / 32;   // 8
    for (int t = 0; t < ntiles; ++t) {
        if (valid_a) {
            As[akq*4+0][ar] = fmaxf(pa.x, 0.f);
            As[akq*4+1][ar] = fmaxf(pa.y, 0.f);
            As[akq*4+2][ar] = fmaxf(pa.z, 0.f);
            As[akq*4+3][ar] = fmaxf(pa.w, 0.f);
        }
        *(float4*)&Bs[bkr0][bcq*4] = pb0;
        *(float4*)&Bs[bkr1][bcq*4] = pb1;
        __syncthreads();

        if (t + 1 < ntiles) {
            const int k0 = kbase + (t + 1) * 32;
            if (valid_a) pa = *(const float4*)&H[(m0 + ar) * HIDD + k0 + akq * 4];
            if (colok) {
                pb0 = *(const float4*)&W2[(k0 + bkr0) * EMBD + bcol];
                pb1 = *(const float4*)&W2[(k0 + bkr1) * EMBD + bcol];
            }
        }

        #pragma unroll 8
        for (int k = 0; k < 32; ++k) {
            const float a = As[k][ty];
            float4 b4 = *(float4*)&Bs[k][tx * 4];
            acc[0] += a * b4.x;
            acc[1] += a * b4.y;
            acc[2] += a * b4.z;
            acc[3] += a * b4.w;
        }
        __syncthreads();
    }

    const int col = n0 + tx * 4;
    if (col < EMBD) {
        float4 bias = {0.f, 0.f, 0.f, 0.f};
        if (blockIdx.z == 0) bias = *(const float4*)&b2[col];
        float* o = &E[(size_t)(m0 + ty) * EMBD + col];
        atomicAdd(o + 0, acc[0] + bias.x);
        atomicAdd(o + 1, acc[1] + bias.y);
        atomicAdd(o + 2, acc[2] + bias.z);
        atomicAdd(o + 3, acc[3] + bias.w);
    }
}

// ---------------------------------------------------------------------------
// Scores: out[b,n] = -sum_d relu(E[b,d] - G[n,d])^2
// Tile 16 batch x 64 labels, D chunks of 64 (zero-padded past 300).
// 256 threads: each thread 1 row x 4 labels. Grid (32, 32) = 1024 blocks.
// ---------------------------------------------------------------------------
__global__ __launch_bounds__(256) void scores_kernel(
    const float* __restrict__ E, const float* __restrict__ G,
    float* __restrict__ out)
{
    __shared__ float Es[16][68];
    __shared__ float Gs[64][68];

    const int tid = threadIdx.x;
    const int tx  = tid & 15;
    const int ty  = tid >> 4;
    const int n0  = blockIdx.x * 64;
    const int b0  = blockIdx.y * 16;

    float acc[4] = {};

    for (int dc = 0; dc < 320; dc += 64) {
        // stage E: 16 rows x 16 q slots = 256 -> 1 per thread
        {
            const int row = tid >> 4, q = tid & 15;
            const int d = dc + q * 4;
            float4 v = {0,0,0,0};
            if (d < EMBD) v = *(const float4*)&E[(b0 + row) * EMBD + d];
            *(float4*)&Es[row][q * 4] = v;
        }
        // stage G: 64 rows x 16 q slots = 1024 -> 4 per thread
        #pragma unroll
        for (int i = 0; i < 4; ++i) {
            const int s = tid + 256 * i;
            const int row = s >> 4, q = s & 15;
            const int n = n0 + row;
            const int d = dc + q * 4;
            float4 v = {0,0,0,0};
            if (n < NLAB && d < EMBD) v = *(const float4*)&G[n * EMBD + d];
            *(float4*)&Gs[row][q * 4] = v;
        }
        __syncthreads();

        #pragma unroll 8
        for (int d = 0; d < 64; d += 4) {
            float4 e4 = *(float4*)&Es[ty][d];
            #pragma unroll
            for (int r = 0; r < 4; ++r) {
                float4 g4 = *(float4*)&Gs[tx + 16 * r][d];
                float d0 = fmaxf(e4.x - g4.x, 0.f);
                float d1 = fmaxf(e4.y - g4.y, 0.f);
                float d2 = fmaxf(e4.z - g4.z, 0.f);
                float d3 = fmaxf(e4.w - g4.w, 0.f);
                acc[r] += d0 * d0;
                acc[r] += d1 * d1;
                acc[r] += d2 * d2;
                acc[r] += d3 * d3;
            }
        }
        __syncthreads();
    }

    const int b = b0 + ty;
    #pragma unroll
    for (int r = 0; r < 4; ++r) {
        const int n = n0 + tx + 16 * r;
        if (n < NLAB) out[(size_t)b * NLAB + n] = -acc[r];
    }
}

// ---------------------------------------------------------------------------
extern "C" void kernel_launch(void* const* d_in, const int* in_sizes, int n_in,
                              void* d_out, int out_size, void* d_ws, size_t ws_size,
                              hipStream_t stream)
{
    const float* vfs = (const float*)d_in[0];   // [512,4096]
    const float* W1  = (const float*)d_in[1];   // [4096,2048]
    const float* b1  = (const float*)d_in[2];   // [2048]
    const float* W2  = (const float*)d_in[3];   // [2048,300]
    const float* b2  = (const float*)d_in[4];   // [300]
    const float* G   = (const float*)d_in[5];   // [2000,300]

    float* out    = (float*)d_out;
    float* scores = out;                        // [512*2000]
    float* E      = out + (size_t)B_SZ * NLAB;  // [512*300]
    float* H      = (float*)d_ws;               // [512*2048] scratch

    // zero accumulation targets (graph-capture legal)
    hipMemsetAsync(H, 0, (size_t)B_SZ * HIDD * sizeof(float), stream);
    hipMemsetAsync(E, 0, (size_t)B_SZ * EMBD * sizeof(float), stream);

    gemm1_kernel<<<dim3(HIDD / 64, B_SZ / 64, G1_SPLIT), 256, 0, stream>>>(vfs, W1, b1, H);
    gemm2_kernel<<<dim3((EMBD + 63) / 64, B_SZ / 16, G2_SPLIT), 256, 0, stream>>>(H, W2, b2, E);
    scores_kernel<<<dim3((NLAB + 63) / 64, B_SZ / 16), 256, 0, stream>>>(E, G, scores);
}

// Round 3
// 203.897 us; speedup vs baseline: 2.0232x; 1.4017x over previous
//
#include <hip/hip_runtime.h>

#define B_SZ   512
#define VFD    4096
#define HIDD   2048
#define EMBD   300
#define NLAB   2000
#define NPAD   320

typedef __attribute__((ext_vector_type(8))) short short8x;
typedef __attribute__((ext_vector_type(4))) float f32x4;
typedef __attribute__((ext_vector_type(8))) unsigned short ushort8;
typedef __attribute__((ext_vector_type(4))) unsigned short ushort4x;

__device__ inline unsigned short f2bf(float x) {
    unsigned u = __float_as_uint(x);
    u += 0x7FFF + ((u >> 16) & 1);          // round-to-nearest-even
    return (unsigned short)(u >> 16);
}

// ---------------------------------------------------------------------------
// Xb[i] = bf16(relu(X[i])), 8 elements/thread, exact grid.
// ---------------------------------------------------------------------------
__global__ __launch_bounds__(256) void conv_relu_bf16_kernel(
    const float* __restrict__ in, unsigned short* __restrict__ out)
{
    const int i = (blockIdx.x * 256 + threadIdx.x) * 8;
    float4 a = *(const float4*)&in[i];
    float4 b = *(const float4*)&in[i + 4];
    ushort8 o;
    o[0] = f2bf(fmaxf(a.x, 0.f)); o[1] = f2bf(fmaxf(a.y, 0.f));
    o[2] = f2bf(fmaxf(a.z, 0.f)); o[3] = f2bf(fmaxf(a.w, 0.f));
    o[4] = f2bf(fmaxf(b.x, 0.f)); o[5] = f2bf(fmaxf(b.y, 0.f));
    o[6] = f2bf(fmaxf(b.z, 0.f)); o[7] = f2bf(fmaxf(b.w, 0.f));
    *(ushort8*)&out[i] = o;
}

// ---------------------------------------------------------------------------
// Transpose-convert: in[K][N] fp32 -> out[NP][ldK] bf16 (out[n][k] = in[k][n]).
// 64x64 tiles via LDS (stride 65 breaks bank conflicts). Cols >= N -> 0 pad.
// Grid: (NP/64, K/64).
// ---------------------------------------------------------------------------
__global__ __launch_bounds__(256) void transpose_conv_kernel(
    const float* __restrict__ in, unsigned short* __restrict__ out,
    int N, int ldK)
{
    __shared__ float tile[64][65];
    const int tid = threadIdx.x;
    const int n0 = blockIdx.x * 64, k0 = blockIdx.y * 64;

    #pragma unroll
    for (int i = 0; i < 4; ++i) {
        const int s = tid + 256 * i;
        const int kr = s >> 4, nc = (s & 15) * 4;
        float4 v = {0.f, 0.f, 0.f, 0.f};
        if (n0 + nc < N) v = *(const float4*)&in[(size_t)(k0 + kr) * N + n0 + nc];
        tile[kr][nc + 0] = v.x; tile[kr][nc + 1] = v.y;
        tile[kr][nc + 2] = v.z; tile[kr][nc + 3] = v.w;
    }
    __syncthreads();

    const int row = tid >> 2, kq = (tid & 3) * 16;
    ushort8 o0, o1;
    #pragma unroll
    for (int j = 0; j < 8; ++j) o0[j] = f2bf(tile[kq + j][row]);
    #pragma unroll
    for (int j = 0; j < 8; ++j) o1[j] = f2bf(tile[kq + 8 + j][row]);
    const size_t off = (size_t)(n0 + row) * ldK + k0 + kq;
    *(ushort8*)&out[off]     = o0;
    *(ushort8*)&out[off + 8] = o1;
}

// ---------------------------------------------------------------------------
// bf16 MFMA GEMM: Cpart[z][M][LDC] = A[M][LDA] @ Bt[N][LDB]^T over k-chunk z.
// BM=BN=64, BK=32, 256 thr = 4 waves, each wave 32x32 = 2x2 mfma 16x16x32.
// LDS layout [k-octet][row] in 16B units: staging writes linear (tid*16B),
// ds_read_b128 fragment reads 2-way (free). A-frag: A[m=lane&15][k=q*8+j];
// B-frag: Bt[n=lane&15][k=q*8+j]; C/D: col=lane&15, row=q*4+reg (m89/m91).
// ---------------------------------------------------------------------------
template<int LDA, int LDB, int LDC, int KCHUNK>
__global__ __launch_bounds__(256) void gemm_bf16_kernel(
    const unsigned short* __restrict__ A,
    const unsigned short* __restrict__ Bt,
    float* __restrict__ Cpart, int M)
{
    __shared__ unsigned short As[2048];   // 64 rows x 32 k bf16 = 4 KB
    __shared__ unsigned short Bs[2048];

    const int tid = threadIdx.x;
    const int m0 = blockIdx.y * 64, n0 = blockIdx.x * 64;
    const int kbase = blockIdx.z * KCHUNK;

    // staging: thread t copies 16B; oct = t>>6, row = t&63 -> LDS offset t*16B
    const int soct = tid >> 6, srow = tid & 63;
    const unsigned short* ga = A  + (size_t)(m0 + srow) * LDA + kbase + soct * 8;
    const unsigned short* gb = Bt + (size_t)(n0 + srow) * LDB + kbase + soct * 8;
    unsigned short* la = &As[tid * 8];
    unsigned short* lb = &Bs[tid * 8];

    const int lane = tid & 63;
    const int wave = tid >> 6;
    const int wm = (wave & 1) * 32;
    const int wn = (wave >> 1) * 32;
    const int q = lane >> 4, l15 = lane & 15;

    f32x4 acc00 = {0.f,0.f,0.f,0.f}, acc01 = {0.f,0.f,0.f,0.f};
    f32x4 acc10 = {0.f,0.f,0.f,0.f}, acc11 = {0.f,0.f,0.f,0.f};

    uint4 pa = *(const uint4*)ga;
    uint4 pb = *(const uint4*)gb;

    const int iters = KCHUNK / 32;
    for (int t = 0; t < iters; ++t) {
        *(uint4*)la = pa;
        *(uint4*)lb = pb;
        __syncthreads();

        if (t + 1 < iters) {
            pa = *(const uint4*)(ga + (t + 1) * 32);
            pb = *(const uint4*)(gb + (t + 1) * 32);
        }

        short8x a0 = *(short8x*)&As[(q * 64 + wm +      l15) * 8];
        short8x a1 = *(short8x*)&As[(q * 64 + wm + 16 + l15) * 8];
        short8x b0 = *(short8x*)&Bs[(q * 64 + wn +      l15) * 8];
        short8x b1 = *(short8x*)&Bs[(q * 64 + wn + 16 + l15) * 8];
        acc00 = __builtin_amdgcn_mfma_f32_16x16x32_bf16(a0, b0, acc00, 0, 0, 0);
        acc01 = __builtin_amdgcn_mfma_f32_16x16x32_bf16(a0, b1, acc01, 0, 0, 0);
        acc10 = __builtin_amdgcn_mfma_f32_16x16x32_bf16(a1, b0, acc10, 0, 0, 0);
        acc11 = __builtin_amdgcn_mfma_f32_16x16x32_bf16(a1, b1, acc11, 0, 0, 0);
        __syncthreads();
    }

    float* Cz = Cpart + (size_t)blockIdx.z * M * LDC;
    #pragma unroll
    for (int r = 0; r < 4; ++r) {
        const int rr = m0 + wm + q * 4 + r;
        const int cc = n0 + wn + l15;
        Cz[(size_t)rr * LDC + cc]             = acc00[r];
        Cz[(size_t)rr * LDC + cc + 16]        = acc01[r];
        Cz[(size_t)(rr + 16) * LDC + cc]      = acc10[r];
        Cz[(size_t)(rr + 16) * LDC + cc + 16] = acc11[r];
    }
}

// ---------------------------------------------------------------------------
// Hb = bf16(relu(Hpart[0] + Hpart[1] + b1)), 4 elems/thread. Grid 1024.
// ---------------------------------------------------------------------------
__global__ __launch_bounds__(256) void reduce_h_kernel(
    const float* __restrict__ Hpart, const float* __restrict__ b1,
    unsigned short* __restrict__ Hb)
{
    const int i = (blockIdx.x * 256 + threadIdx.x) * 4;
    const int col = i & (HIDD - 1);
    float4 p0 = *(const float4*)&Hpart[i];
    float4 p1 = *(const float4*)&Hpart[(size_t)B_SZ * HIDD + i];
    float4 bb = *(const float4*)&b1[col];
    ushort4x o;
    o[0] = f2bf(fmaxf(p0.x + p1.x + bb.x, 0.f));
    o[1] = f2bf(fmaxf(p0.y + p1.y + bb.y, 0.f));
    o[2] = f2bf(fmaxf(p0.z + p1.z + bb.z, 0.f));
    o[3] = f2bf(fmaxf(p0.w + p1.w + bb.w, 0.f));
    *(ushort4x*)&Hb[i] = o;
}

// ---------------------------------------------------------------------------
// E[m][n] = sum_z Epart[z][m][NPAD..] + b2[n], n < 300. Grid 600.
// ---------------------------------------------------------------------------
__global__ __launch_bounds__(256) void reduce_e_kernel(
    const float* __restrict__ Epart, const float* __restrict__ b2,
    float* __restrict__ E)
{
    const int gid = blockIdx.x * 256 + threadIdx.x;
    if (gid >= B_SZ * EMBD) return;
    const int m = gid / EMBD, n = gid - m * EMBD;
    float v = b2[n];
    #pragma unroll
    for (int z = 0; z < 4; ++z)
        v += Epart[(size_t)z * B_SZ * NPAD + m * NPAD + n];
    E[gid] = v;
}

// ---------------------------------------------------------------------------
// Scores: out[b,n] = -sum_d relu(E[b,d]-G[n,d])^2. Tile 32 rows x 128 labels,
// thread = 2 rows x 8 labels (10 LDS b128 reads per 192 VALU ops). Grid 16x16.
// ---------------------------------------------------------------------------
__global__ __launch_bounds__(256) void scores_kernel(
    const float* __restrict__ E, const float* __restrict__ G,
    float* __restrict__ out)
{
    __shared__ float Es[32][68];
    __shared__ float Gs[128][68];

    const int tid = threadIdx.x;
    const int tx = tid & 15, ty = tid >> 4;
    const int n0 = blockIdx.x * 128, b0 = blockIdx.y * 32;

    float acc[2][8] = {};

    for (int dc = 0; dc < 320; dc += 64) {
        #pragma unroll
        for (int i = 0; i < 2; ++i) {
            const int s = tid + 256 * i;
            const int row = s >> 4, qd = (s & 15) * 4;
            const int d = dc + qd;
            float4 v = {0.f, 0.f, 0.f, 0.f};
            if (d < EMBD) v = *(const float4*)&E[(size_t)(b0 + row) * EMBD + d];
            *(float4*)&Es[row][qd] = v;
        }
        #pragma unroll
        for (int i = 0; i < 8; ++i) {
            const int s = tid + 256 * i;
            const int row = s >> 4, qd = (s & 15) * 4;
            const int d = dc + qd;
            const int n = n0 + row;
            float4 v = {0.f, 0.f, 0.f, 0.f};
            if (n < NLAB && d < EMBD) v = *(const float4*)&G[(size_t)n * EMBD + d];
            *(float4*)&Gs[row][qd] = v;
        }
        __syncthreads();

        #pragma unroll 4
        for (int d = 0; d < 64; d += 4) {
            float4 e0 = *(float4*)&Es[ty * 2][d];
            float4 e1 = *(float4*)&Es[ty * 2 + 1][d];
            #pragma unroll
            for (int r = 0; r < 8; ++r) {
                float4 g = *(float4*)&Gs[tx + 16 * r][d];
                float t0;
                t0 = fmaxf(e0.x - g.x, 0.f); acc[0][r] += t0 * t0;
                t0 = fmaxf(e0.y - g.y, 0.f); acc[0][r] += t0 * t0;
                t0 = fmaxf(e0.z - g.z, 0.f); acc[0][r] += t0 * t0;
                t0 = fmaxf(e0.w - g.w, 0.f); acc[0][r] += t0 * t0;
                t0 = fmaxf(e1.x - g.x, 0.f); acc[1][r] += t0 * t0;
                t0 = fmaxf(e1.y - g.y, 0.f); acc[1][r] += t0 * t0;
                t0 = fmaxf(e1.z - g.z, 0.f); acc[1][r] += t0 * t0;
                t0 = fmaxf(e1.w - g.w, 0.f); acc[1][r] += t0 * t0;
            }
        }
        __syncthreads();
    }

    #pragma unroll
    for (int p = 0; p < 2; ++p) {
        const int b = b0 + ty * 2 + p;
        #pragma unroll
        for (int r = 0; r < 8; ++r) {
            const int n = n0 + tx + 16 * r;
            if (n < NLAB) out[(size_t)b * NLAB + n] = -acc[p][r];
        }
    }
}

// ---------------------------------------------------------------------------
extern "C" void kernel_launch(void* const* d_in, const int* in_sizes, int n_in,
                              void* d_out, int out_size, void* d_ws, size_t ws_size,
                              hipStream_t stream)
{
    const float* vfs = (const float*)d_in[0];   // [512,4096]
    const float* W1  = (const float*)d_in[1];   // [4096,2048]
    const float* b1  = (const float*)d_in[2];   // [2048]
    const float* W2  = (const float*)d_in[3];   // [2048,300]
    const float* b2  = (const float*)d_in[4];   // [300]
    const float* G   = (const float*)d_in[5];   // [2000,300]

    float* out    = (float*)d_out;
    float* scores = out;                        // [512*2000]
    float* E      = out + (size_t)B_SZ * NLAB;  // [512*300]

    // workspace layout (bytes): total ~33.8 MB
    char* ws = (char*)d_ws;
    unsigned short* Xb  = (unsigned short*)(ws);             //  4 MB  [512][4096]
    unsigned short* W1T = (unsigned short*)(ws + 4194304);   // 16 MB  [2048][4096]
    unsigned short* W2T = (unsigned short*)(ws + 20971520);  // 1.25MB [320][2048]
    unsigned short* Hb  = (unsigned short*)(ws + 22282240);  //  2 MB  [512][2048]
    float*          Hpart = (float*)(ws + 24379392);         //  8 MB  [2][512][2048]
    float*          Epart = (float*)(ws + 32768000);         // 2.6 MB [4][512][320]

    conv_relu_bf16_kernel<<<1024, 256, 0, stream>>>(vfs, Xb);
    transpose_conv_kernel<<<dim3(32, 64), 256, 0, stream>>>(W1, W1T, HIDD, VFD);
    transpose_conv_kernel<<<dim3(5, 32), 256, 0, stream>>>(W2, W2T, EMBD, HIDD);

    // GEMM1: [512,2048] = Xb[512,4096] @ W1T^T, split-K 2 -> 512 blocks
    gemm_bf16_kernel<VFD, VFD, HIDD, 2048>
        <<<dim3(32, 8, 2), 256, 0, stream>>>(Xb, W1T, Hpart, B_SZ);
    reduce_h_kernel<<<1024, 256, 0, stream>>>(Hpart, b1, Hb);

    // GEMM2: [512,320] = Hb[512,2048] @ W2T^T, split-K 4 -> 160 blocks
    gemm_bf16_kernel<HIDD, HIDD, NPAD, 512>
        <<<dim3(5, 8, 4), 256, 0, stream>>>(Hb, W2T, Epart, B_SZ);
    reduce_e_kernel<<<600, 256, 0, stream>>>(Epart, b2, E);

    scores_kernel<<<dim3(16, 16), 256, 0, stream>>>(E, G, scores);
}

// Round 4
// 180.427 us; speedup vs baseline: 2.2863x; 1.1301x over previous
//
#include <hip/hip_runtime.h>

#define B_SZ   512
#define VFD    4096
#define HIDD   2048
#define EMBD   300
#define NLAB   2000
#define NPAD   320

typedef __attribute__((ext_vector_type(8))) short short8x;
typedef __attribute__((ext_vector_type(4))) float f32x4;
typedef __attribute__((ext_vector_type(8))) unsigned short ushort8;
typedef __attribute__((ext_vector_type(4))) unsigned short ushort4x;

typedef const __attribute__((address_space(1))) unsigned int* gas_t;
typedef __attribute__((address_space(3))) unsigned int* las_t;

__device__ inline unsigned short f2bf(float x) {
    unsigned u = __float_as_uint(x);
    u += 0x7FFF + ((u >> 16) & 1);          // round-to-nearest-even
    return (unsigned short)(u >> 16);
}

// ---------------------------------------------------------------------------
// Xb[i] = bf16(relu(X[i])), 8 elements/thread, exact grid.
// ---------------------------------------------------------------------------
__global__ __launch_bounds__(256) void conv_relu_bf16_kernel(
    const float* __restrict__ in, unsigned short* __restrict__ out)
{
    const int i = (blockIdx.x * 256 + threadIdx.x) * 8;
    float4 a = *(const float4*)&in[i];
    float4 b = *(const float4*)&in[i + 4];
    ushort8 o;
    o[0] = f2bf(fmaxf(a.x, 0.f)); o[1] = f2bf(fmaxf(a.y, 0.f));
    o[2] = f2bf(fmaxf(a.z, 0.f)); o[3] = f2bf(fmaxf(a.w, 0.f));
    o[4] = f2bf(fmaxf(b.x, 0.f)); o[5] = f2bf(fmaxf(b.y, 0.f));
    o[6] = f2bf(fmaxf(b.z, 0.f)); o[7] = f2bf(fmaxf(b.w, 0.f));
    *(ushort8*)&out[i] = o;
}

// ---------------------------------------------------------------------------
// Transpose-convert: in[K][N] fp32 -> out[NP][ldK] bf16 (out[n][k] = in[k][n]).
// 64x64 tiles via LDS. Grid: (NP/64, K/64).
// ---------------------------------------------------------------------------
__global__ __launch_bounds__(256) void transpose_conv_kernel(
    const float* __restrict__ in, unsigned short* __restrict__ out,
    int N, int ldK)
{
    __shared__ float tile[64][65];
    const int tid = threadIdx.x;
    const int n0 = blockIdx.x * 64, k0 = blockIdx.y * 64;

    #pragma unroll
    for (int i = 0; i < 4; ++i) {
        const int s = tid + 256 * i;
        const int kr = s >> 4, nc = (s & 15) * 4;
        float4 v = {0.f, 0.f, 0.f, 0.f};
        if (n0 + nc < N) v = *(const float4*)&in[(size_t)(k0 + kr) * N + n0 + nc];
        tile[kr][nc + 0] = v.x; tile[kr][nc + 1] = v.y;
        tile[kr][nc + 2] = v.z; tile[kr][nc + 3] = v.w;
    }
    __syncthreads();

    const int row = tid >> 2, kq = (tid & 3) * 16;
    ushort8 o0, o1;
    #pragma unroll
    for (int j = 0; j < 8; ++j) o0[j] = f2bf(tile[kq + j][row]);
    #pragma unroll
    for (int j = 0; j < 8; ++j) o1[j] = f2bf(tile[kq + 8 + j][row]);
    const size_t off = (size_t)(n0 + row) * ldK + k0 + kq;
    *(ushort8*)&out[off]     = o0;
    *(ushort8*)&out[off + 8] = o1;
}

// ---------------------------------------------------------------------------
// bf16 MFMA GEMM: Cpart[z][M][LDC] = A[M][LDA] @ Bt[N][LDB]^T over k-chunk z.
// BM=BN=64, BK=32, 256 thr = 4 waves, each wave 32x32 = 2x2 mfma 16x16x32.
// Staging via global_load_lds width=16 (m97 2-barrier structure): thread t's
// LDS slot = t*16B = wave-uniform base + lane*16 (HW requirement).
// A-frag: A[m=lane&15][k=q*8+j]; B-frag: Bt[n=lane&15][k=q*8+j];
// C/D: col=lane&15, row=q*4+reg.
// ---------------------------------------------------------------------------
template<int LDA, int LDB, int LDC, int KCHUNK>
__global__ __launch_bounds__(256) void gemm_bf16_kernel(
    const unsigned short* __restrict__ A,
    const unsigned short* __restrict__ Bt,
    float* __restrict__ Cpart, int M)
{
    __shared__ unsigned short As[2048];   // 64 rows x 32 k bf16 = 4 KB
    __shared__ unsigned short Bs[2048];

    const int tid = threadIdx.x;
    const int m0 = blockIdx.y * 64, n0 = blockIdx.x * 64;
    const int kbase = blockIdx.z * KCHUNK;

    const int soct = tid >> 6, srow = tid & 63;
    const unsigned short* ga = A  + (size_t)(m0 + srow) * LDA + kbase + soct * 8;
    const unsigned short* gb = Bt + (size_t)(n0 + srow) * LDB + kbase + soct * 8;
    las_t la = (las_t)(void*)&As[tid * 8];
    las_t lb = (las_t)(void*)&Bs[tid * 8];

    const int lane = tid & 63;
    const int wave = tid >> 6;
    const int wm = (wave & 1) * 32;
    const int wn = (wave >> 1) * 32;
    const int q = lane >> 4, l15 = lane & 15;

    f32x4 acc00 = {0.f,0.f,0.f,0.f}, acc01 = {0.f,0.f,0.f,0.f};
    f32x4 acc10 = {0.f,0.f,0.f,0.f}, acc11 = {0.f,0.f,0.f,0.f};

    const int iters = KCHUNK / 32;
    for (int t = 0; t < iters; ++t) {
        __builtin_amdgcn_global_load_lds((gas_t)(const void*)(ga + t * 32), la, 16, 0, 0);
        __builtin_amdgcn_global_load_lds((gas_t)(const void*)(gb + t * 32), lb, 16, 0, 0);
        __syncthreads();   // drains vmcnt, then barrier

        short8x a0 = *(short8x*)&As[(q * 64 + wm +      l15) * 8];
        short8x a1 = *(short8x*)&As[(q * 64 + wm + 16 + l15) * 8];
        short8x b0 = *(short8x*)&Bs[(q * 64 + wn +      l15) * 8];
        short8x b1 = *(short8x*)&Bs[(q * 64 + wn + 16 + l15) * 8];
        acc00 = __builtin_amdgcn_mfma_f32_16x16x32_bf16(a0, b0, acc00, 0, 0, 0);
        acc01 = __builtin_amdgcn_mfma_f32_16x16x32_bf16(a0, b1, acc01, 0, 0, 0);
        acc10 = __builtin_amdgcn_mfma_f32_16x16x32_bf16(a1, b0, acc10, 0, 0, 0);
        acc11 = __builtin_amdgcn_mfma_f32_16x16x32_bf16(a1, b1, acc11, 0, 0, 0);
        __syncthreads();   // protect LDS before next staging
    }

    float* Cz = Cpart + (size_t)blockIdx.z * M * LDC;
    #pragma unroll
    for (int r = 0; r < 4; ++r) {
        const int rr = m0 + wm + q * 4 + r;
        const int cc = n0 + wn + l15;
        Cz[(size_t)rr * LDC + cc]             = acc00[r];
        Cz[(size_t)rr * LDC + cc + 16]        = acc01[r];
        Cz[(size_t)(rr + 16) * LDC + cc]      = acc10[r];
        Cz[(size_t)(rr + 16) * LDC + cc + 16] = acc11[r];
    }
}

// ---------------------------------------------------------------------------
// Hb = bf16(relu(Hpart[0] + Hpart[1] + b1)), 4 elems/thread. Grid 1024.
// ---------------------------------------------------------------------------
__global__ __launch_bounds__(256) void reduce_h_kernel(
    const float* __restrict__ Hpart, const float* __restrict__ b1,
    unsigned short* __restrict__ Hb)
{
    const int i = (blockIdx.x * 256 + threadIdx.x) * 4;
    const int col = i & (HIDD - 1);
    float4 p0 = *(const float4*)&Hpart[i];
    float4 p1 = *(const float4*)&Hpart[(size_t)B_SZ * HIDD + i];
    float4 bb = *(const float4*)&b1[col];
    ushort4x o;
    o[0] = f2bf(fmaxf(p0.x + p1.x + bb.x, 0.f));
    o[1] = f2bf(fmaxf(p0.y + p1.y + bb.y, 0.f));
    o[2] = f2bf(fmaxf(p0.z + p1.z + bb.z, 0.f));
    o[3] = f2bf(fmaxf(p0.w + p1.w + bb.w, 0.f));
    *(ushort4x*)&Hb[i] = o;
}

// ---------------------------------------------------------------------------
// E[m][n] = sum_z Epart[z][m][NPAD..] + b2[n], n < 300. Grid 600.
// ---------------------------------------------------------------------------
__global__ __launch_bounds__(256) void reduce_e_kernel(
    const float* __restrict__ Epart, const float* __restrict__ b2,
    float* __restrict__ E)
{
    const int gid = blockIdx.x * 256 + threadIdx.x;
    if (gid >= B_SZ * EMBD) return;
    const int m = gid / EMBD, n = gid - m * EMBD;
    float v = b2[n];
    #pragma unroll
    for (int z = 0; z < 4; ++z)
        v += Epart[(size_t)z * B_SZ * NPAD + m * NPAD + n];
    E[gid] = v;
}

// ---------------------------------------------------------------------------
// Scores: out[b,n] = -sum_d relu(E[b,d]-G[n,d])^2.
// Tile 32 rows x 64 labels, thread = 2 rows x 4 labels (6 b128 reads per
// 96 VALU ops). Grid (32,16) = 512 blocks = 2/CU, 26 KB LDS.
// ---------------------------------------------------------------------------
__global__ __launch_bounds__(256) void scores_kernel(
    const float* __restrict__ E, const float* __restrict__ G,
    float* __restrict__ out)
{
    __shared__ float Es[32][68];
    __shared__ float Gs[64][68];

    const int tid = threadIdx.x;
    const int tx = tid & 15, ty = tid >> 4;
    const int n0 = blockIdx.x * 64, b0 = blockIdx.y * 32;

    float acc[2][4] = {};

    for (int dc = 0; dc < 320; dc += 64) {
        // stage E: 32 rows x 16 qd slots = 512 -> 2 per thread
        #pragma unroll
        for (int i = 0; i < 2; ++i) {
            const int s = tid + 256 * i;
            const int row = s >> 4, qd = (s & 15) * 4;
            const int d = dc + qd;
            float4 v = {0.f, 0.f, 0.f, 0.f};
            if (d < EMBD) v = *(const float4*)&E[(size_t)(b0 + row) * EMBD + d];
            *(float4*)&Es[row][qd] = v;
        }
        // stage G: 64 rows x 16 qd slots = 1024 -> 4 per thread
        #pragma unroll
        for (int i = 0; i < 4; ++i) {
            const int s = tid + 256 * i;
            const int row = s >> 4, qd = (s & 15) * 4;
            const int d = dc + qd;
            const int n = n0 + row;
            float4 v = {0.f, 0.f, 0.f, 0.f};
            if (n < NLAB && d < EMBD) v = *(const float4*)&G[(size_t)n * EMBD + d];
            *(float4*)&Gs[row][qd] = v;
        }
        __syncthreads();

        #pragma unroll 4
        for (int d = 0; d < 64; d += 4) {
            float4 e0 = *(float4*)&Es[ty * 2][d];
            float4 e1 = *(float4*)&Es[ty * 2 + 1][d];
            #pragma unroll
            for (int r = 0; r < 4; ++r) {
                float4 g = *(float4*)&Gs[tx + 16 * r][d];
                float t0;
                t0 = fmaxf(e0.x - g.x, 0.f); acc[0][r] += t0 * t0;
                t0 = fmaxf(e0.y - g.y, 0.f); acc[0][r] += t0 * t0;
                t0 = fmaxf(e0.z - g.z, 0.f); acc[0][r] += t0 * t0;
                t0 = fmaxf(e0.w - g.w, 0.f); acc[0][r] += t0 * t0;
                t0 = fmaxf(e1.x - g.x, 0.f); acc[1][r] += t0 * t0;
                t0 = fmaxf(e1.y - g.y, 0.f); acc[1][r] += t0 * t0;
                t0 = fmaxf(e1.z - g.z, 0.f); acc[1][r] += t0 * t0;
                t0 = fmaxf(e1.w - g.w, 0.f); acc[1][r] += t0 * t0;
            }
        }
        __syncthreads();
    }

    #pragma unroll
    for (int p = 0; p < 2; ++p) {
        const int b = b0 + ty * 2 + p;
        #pragma unroll
        for (int r = 0; r < 4; ++r) {
            const int n = n0 + tx + 16 * r;
            if (n < NLAB) out[(size_t)b * NLAB + n] = -acc[p][r];
        }
    }
}

// ---------------------------------------------------------------------------
extern "C" void kernel_launch(void* const* d_in, const int* in_sizes, int n_in,
                              void* d_out, int out_size, void* d_ws, size_t ws_size,
                              hipStream_t stream)
{
    const float* vfs = (const float*)d_in[0];   // [512,4096]
    const float* W1  = (const float*)d_in[1];   // [4096,2048]
    const float* b1  = (const float*)d_in[2];   // [2048]
    const float* W2  = (const float*)d_in[3];   // [2048,300]
    const float* b2  = (const float*)d_in[4];   // [300]
    const float* G   = (const float*)d_in[5];   // [2000,300]

    float* out    = (float*)d_out;
    float* scores = out;                        // [512*2000]
    float* E      = out + (size_t)B_SZ * NLAB;  // [512*300]

    // workspace layout (bytes): total ~35.4 MB (proven to fit)
    char* ws = (char*)d_ws;
    unsigned short* Xb  = (unsigned short*)(ws);             //  4 MB  [512][4096]
    unsigned short* W1T = (unsigned short*)(ws + 4194304);   // 16 MB  [2048][4096]
    unsigned short* W2T = (unsigned short*)(ws + 20971520);  // 1.25MB [320][2048]
    unsigned short* Hb  = (unsigned short*)(ws + 22282240);  //  2 MB  [512][2048]
    float*          Hpart = (float*)(ws + 24379392);         //  8 MB  [2][512][2048]
    float*          Epart = (float*)(ws + 32768000);         // 2.6 MB [4][512][320]

    conv_relu_bf16_kernel<<<1024, 256, 0, stream>>>(vfs, Xb);
    transpose_conv_kernel<<<dim3(32, 64), 256, 0, stream>>>(W1, W1T, HIDD, VFD);
    transpose_conv_kernel<<<dim3(5, 32), 256, 0, stream>>>(W2, W2T, EMBD, HIDD);

    // GEMM1: [512,2048] = Xb[512,4096] @ W1T^T, split-K 2 -> 512 blocks
    gemm_bf16_kernel<VFD, VFD, HIDD, 2048>
        <<<dim3(32, 8, 2), 256, 0, stream>>>(Xb, W1T, Hpart, B_SZ);
    reduce_h_kernel<<<1024, 256, 0, stream>>>(Hpart, b1, Hb);

    // GEMM2: [512,320] = Hb[512,2048] @ W2T^T, split-K 4 -> 160 blocks
    gemm_bf16_kernel<HIDD, HIDD, NPAD, 512>
        <<<dim3(5, 8, 4), 256, 0, stream>>>(Hb, W2T, Epart, B_SZ);
    reduce_e_kernel<<<600, 256, 0, stream>>>(Epart, b2, E);

    scores_kernel<<<dim3(32, 16), 256, 0, stream>>>(E, G, scores);
}

// Round 5
// 173.490 us; speedup vs baseline: 2.3778x; 1.0400x over previous
//
#include <hip/hip_runtime.h>

#define B_SZ   512
#define VFD    4096
#define HIDD   2048
#define EMBD   300
#define NLAB   2000
#define NPAD   320

#define G1_SPLIT 4          // gemm1 k-chunks: K=4096 -> 1024 each, 1024 blocks
#define G2_SPLIT 8          // gemm2 k-chunks: K=2048 -> 256 each, 320 blocks

typedef __attribute__((ext_vector_type(8))) short short8x;
typedef __attribute__((ext_vector_type(4))) float f32x4;
typedef __attribute__((ext_vector_type(8))) unsigned short ushort8;
typedef __attribute__((ext_vector_type(4))) unsigned short ushort4x;

typedef const __attribute__((address_space(1))) unsigned int* gas_t;
typedef __attribute__((address_space(3))) unsigned int* las_t;

__device__ inline unsigned short f2bf(float x) {
    unsigned u = __float_as_uint(x);
    u += 0x7FFF + ((u >> 16) & 1);          // round-to-nearest-even
    return (unsigned short)(u >> 16);
}

// ---------------------------------------------------------------------------
// Fused prep (single launch, grid-range dispatch):
//   blocks [0,1024):      Xb = bf16(relu(vfs)), 8 elem/thread
//   blocks [1024,3072):   W1T[n][k] = bf16(W1[k][n])   (transpose-convert)
//   blocks [3072,3232):   W2T[n][k] = bf16(W2[k][n]), n>=300 zero-padded
// ---------------------------------------------------------------------------
__global__ __launch_bounds__(256) void prep_kernel(
    const float* __restrict__ vfs, unsigned short* __restrict__ Xb,
    const float* __restrict__ W1, unsigned short* __restrict__ W1T,
    const float* __restrict__ W2, unsigned short* __restrict__ W2T)
{
    __shared__ float tile[64][65];
    const int tid = threadIdx.x;
    const int blk = blockIdx.x;

    if (blk < 1024) {                       // conv+relu Xb
        const int i = (blk * 256 + tid) * 8;
        float4 a = *(const float4*)&vfs[i];
        float4 b = *(const float4*)&vfs[i + 4];
        ushort8 o;
        o[0] = f2bf(fmaxf(a.x, 0.f)); o[1] = f2bf(fmaxf(a.y, 0.f));
        o[2] = f2bf(fmaxf(a.z, 0.f)); o[3] = f2bf(fmaxf(a.w, 0.f));
        o[4] = f2bf(fmaxf(b.x, 0.f)); o[5] = f2bf(fmaxf(b.y, 0.f));
        o[6] = f2bf(fmaxf(b.z, 0.f)); o[7] = f2bf(fmaxf(b.w, 0.f));
        *(ushort8*)&Xb[i] = o;
        return;
    }

    // transpose-convert part
    const float* in; unsigned short* out; int N, ldK, bx, by;
    if (blk < 3072) {                       // W1: K=4096, N=2048, grid (32,64)
        const int b = blk - 1024;
        in = W1; out = W1T; N = HIDD; ldK = VFD; bx = b & 31; by = b >> 5;
    } else {                                // W2: K=2048, N=300->320, grid (5,32)
        const int b = blk - 3072;
        in = W2; out = W2T; N = EMBD; ldK = HIDD; bx = b % 5; by = b / 5;
    }
    const int n0 = bx * 64, k0 = by * 64;

    #pragma unroll
    for (int i = 0; i < 4; ++i) {
        const int s = tid + 256 * i;
        const int kr = s >> 4, nc = (s & 15) * 4;
        float4 v = {0.f, 0.f, 0.f, 0.f};
        if (n0 + nc < N) v = *(const float4*)&in[(size_t)(k0 + kr) * N + n0 + nc];
        tile[kr][nc + 0] = v.x; tile[kr][nc + 1] = v.y;
        tile[kr][nc + 2] = v.z; tile[kr][nc + 3] = v.w;
    }
    __syncthreads();

    const int row = tid >> 2, kq = (tid & 3) * 16;
    ushort8 o0, o1;
    #pragma unroll
    for (int j = 0; j < 8; ++j) o0[j] = f2bf(tile[kq + j][row]);
    #pragma unroll
    for (int j = 0; j < 8; ++j) o1[j] = f2bf(tile[kq + 8 + j][row]);
    const size_t off = (size_t)(n0 + row) * ldK + k0 + kq;
    *(ushort8*)&out[off]     = o0;
    *(ushort8*)&out[off + 8] = o1;
}

// ---------------------------------------------------------------------------
// bf16 MFMA GEMM: Cpart[z][M][LDC] = A[M][LDA] @ Bt[N][LDB]^T over k-chunk z.
// BM=BN=64, BK=32, 4 waves, wave = 32x32 (2x2 mfma 16x16x32).
// Double-buffered LDS + 1-ahead global_load_lds, ONE barrier per iter:
//   barrier(t) drains tile-t loads (in flight since iter t-1 -> latency
//   hidden) and proves all waves finished reading buf[nxt] (iter t-1),
//   so tile-t+1 DMA into buf[nxt] is safe.
// A-frag: A[m=lane&15][k=q*8+j]; B-frag: Bt[n=lane&15][k=q*8+j];
// C/D: col=lane&15, row=q*4+reg.
// ---------------------------------------------------------------------------
template<int LDA, int LDB, int LDC, int KCHUNK>
__global__ __launch_bounds__(256) void gemm_bf16_kernel(
    const unsigned short* __restrict__ A,
    const unsigned short* __restrict__ Bt,
    float* __restrict__ Cpart, int M)
{
    __shared__ unsigned short As[2][2048];   // 2 x 4 KB
    __shared__ unsigned short Bs[2][2048];

    const int tid = threadIdx.x;
    const int m0 = blockIdx.y * 64, n0 = blockIdx.x * 64;
    const int kbase = blockIdx.z * KCHUNK;

    const int soct = tid >> 6, srow = tid & 63;
    const unsigned short* ga = A  + (size_t)(m0 + srow) * LDA + kbase + soct * 8;
    const unsigned short* gb = Bt + (size_t)(n0 + srow) * LDB + kbase + soct * 8;

    const int lane = tid & 63;
    const int wave = tid >> 6;
    const int wm = (wave & 1) * 32;
    const int wn = (wave >> 1) * 32;
    const int q = lane >> 4, l15 = lane & 15;

    f32x4 acc00 = {0.f,0.f,0.f,0.f}, acc01 = {0.f,0.f,0.f,0.f};
    f32x4 acc10 = {0.f,0.f,0.f,0.f}, acc11 = {0.f,0.f,0.f,0.f};

    // prefetch tile 0 into buf 0
    __builtin_amdgcn_global_load_lds((gas_t)(const void*)ga,
                                     (las_t)(void*)&As[0][tid * 8], 16, 0, 0);
    __builtin_amdgcn_global_load_lds((gas_t)(const void*)gb,
                                     (las_t)(void*)&Bs[0][tid * 8], 16, 0, 0);

    const int iters = KCHUNK / 32;
    for (int t = 0; t < iters; ++t) {
        const int cur = t & 1, nxt = cur ^ 1;
        __syncthreads();            // vmcnt drain: tile t present; buf[nxt] free

        if (t + 1 < iters) {        // 1-ahead DMA overlaps this iter's compute
            __builtin_amdgcn_global_load_lds((gas_t)(const void*)(ga + (t + 1) * 32),
                                             (las_t)(void*)&As[nxt][tid * 8], 16, 0, 0);
            __builtin_amdgcn_global_load_lds((gas_t)(const void*)(gb + (t + 1) * 32),
                                             (las_t)(void*)&Bs[nxt][tid * 8], 16, 0, 0);
        }

        short8x a0 = *(short8x*)&As[cur][(q * 64 + wm +      l15) * 8];
        short8x a1 = *(short8x*)&As[cur][(q * 64 + wm + 16 + l15) * 8];
        short8x b0 = *(short8x*)&Bs[cur][(q * 64 + wn +      l15) * 8];
        short8x b1 = *(short8x*)&Bs[cur][(q * 64 + wn + 16 + l15) * 8];
        acc00 = __builtin_amdgcn_mfma_f32_16x16x32_bf16(a0, b0, acc00, 0, 0, 0);
        acc01 = __builtin_amdgcn_mfma_f32_16x16x32_bf16(a0, b1, acc01, 0, 0, 0);
        acc10 = __builtin_amdgcn_mfma_f32_16x16x32_bf16(a1, b0, acc10, 0, 0, 0);
        acc11 = __builtin_amdgcn_mfma_f32_16x16x32_bf16(a1, b1, acc11, 0, 0, 0);
    }

    float* Cz = Cpart + (size_t)blockIdx.z * M * LDC;
    #pragma unroll
    for (int r = 0; r < 4; ++r) {
        const int rr = m0 + wm + q * 4 + r;
        const int cc = n0 + wn + l15;
        Cz[(size_t)rr * LDC + cc]             = acc00[r];
        Cz[(size_t)rr * LDC + cc + 16]        = acc01[r];
        Cz[(size_t)(rr + 16) * LDC + cc]      = acc10[r];
        Cz[(size_t)(rr + 16) * LDC + cc + 16] = acc11[r];
    }
}

// ---------------------------------------------------------------------------
// Hb = bf16(relu(sum_z Hpart[z] + b1)), 4 elems/thread. Grid 1024.
// ---------------------------------------------------------------------------
__global__ __launch_bounds__(256) void reduce_h_kernel(
    const float* __restrict__ Hpart, const float* __restrict__ b1,
    unsigned short* __restrict__ Hb)
{
    const int i = (blockIdx.x * 256 + threadIdx.x) * 4;
    const int col = i & (HIDD - 1);
    float4 s = *(const float4*)&b1[col];
    #pragma unroll
    for (int z = 0; z < G1_SPLIT; ++z) {
        float4 p = *(const float4*)&Hpart[(size_t)z * B_SZ * HIDD + i];
        s.x += p.x; s.y += p.y; s.z += p.z; s.w += p.w;
    }
    ushort4x o;
    o[0] = f2bf(fmaxf(s.x, 0.f));
    o[1] = f2bf(fmaxf(s.y, 0.f));
    o[2] = f2bf(fmaxf(s.z, 0.f));
    o[3] = f2bf(fmaxf(s.w, 0.f));
    *(ushort4x*)&Hb[i] = o;
}

// ---------------------------------------------------------------------------
// E[m][n] = sum_z Epart[z][m][NPAD..] + b2[n], n < 300. Grid 600.
// ---------------------------------------------------------------------------
__global__ __launch_bounds__(256) void reduce_e_kernel(
    const float* __restrict__ Epart, const float* __restrict__ b2,
    float* __restrict__ E)
{
    const int gid = blockIdx.x * 256 + threadIdx.x;
    if (gid >= B_SZ * EMBD) return;
    const int m = gid / EMBD, n = gid - m * EMBD;
    float v = b2[n];
    #pragma unroll
    for (int z = 0; z < G2_SPLIT; ++z)
        v += Epart[(size_t)z * B_SZ * NPAD + m * NPAD + n];
    E[gid] = v;
}

// ---------------------------------------------------------------------------
// Scores: out[b,n] = -sum_d relu(E[b,d]-G[n,d])^2.
// Tile 32 rows x 64 labels, thread = 2 rows x 4 labels. Grid (32,16) = 512.
// ---------------------------------------------------------------------------
__global__ __launch_bounds__(256) void scores_kernel(
    const float* __restrict__ E, const float* __restrict__ G,
    float* __restrict__ out)
{
    __shared__ float Es[32][68];
    __shared__ float Gs[64][68];

    const int tid = threadIdx.x;
    const int tx = tid & 15, ty = tid >> 4;
    const int n0 = blockIdx.x * 64, b0 = blockIdx.y * 32;

    float acc[2][4] = {};

    for (int dc = 0; dc < 320; dc += 64) {
        #pragma unroll
        for (int i = 0; i < 2; ++i) {
            const int s = tid + 256 * i;
            const int row = s >> 4, qd = (s & 15) * 4;
            const int d = dc + qd;
            float4 v = {0.f, 0.f, 0.f, 0.f};
            if (d < EMBD) v = *(const float4*)&E[(size_t)(b0 + row) * EMBD + d];
            *(float4*)&Es[row][qd] = v;
        }
        #pragma unroll
        for (int i = 0; i < 4; ++i) {
            const int s = tid + 256 * i;
            const int row = s >> 4, qd = (s & 15) * 4;
            const int d = dc + qd;
            const int n = n0 + row;
            float4 v = {0.f, 0.f, 0.f, 0.f};
            if (n < NLAB && d < EMBD) v = *(const float4*)&G[(size_t)n * EMBD + d];
            *(float4*)&Gs[row][qd] = v;
        }
        __syncthreads();

        #pragma unroll 4
        for (int d = 0; d < 64; d += 4) {
            float4 e0 = *(float4*)&Es[ty * 2][d];
            float4 e1 = *(float4*)&Es[ty * 2 + 1][d];
            #pragma unroll
            for (int r = 0; r < 4; ++r) {
                float4 g = *(float4*)&Gs[tx + 16 * r][d];
                float t0;
                t0 = fmaxf(e0.x - g.x, 0.f); acc[0][r] += t0 * t0;
                t0 = fmaxf(e0.y - g.y, 0.f); acc[0][r] += t0 * t0;
                t0 = fmaxf(e0.z - g.z, 0.f); acc[0][r] += t0 * t0;
                t0 = fmaxf(e0.w - g.w, 0.f); acc[0][r] += t0 * t0;
                t0 = fmaxf(e1.x - g.x, 0.f); acc[1][r] += t0 * t0;
                t0 = fmaxf(e1.y - g.y, 0.f); acc[1][r] += t0 * t0;
                t0 = fmaxf(e1.z - g.z, 0.f); acc[1][r] += t0 * t0;
                t0 = fmaxf(e1.w - g.w, 0.f); acc[1][r] += t0 * t0;
            }
        }
        __syncthreads();
    }

    #pragma unroll
    for (int p = 0; p < 2; ++p) {
        const int b = b0 + ty * 2 + p;
        #pragma unroll
        for (int r = 0; r < 4; ++r) {
            const int n = n0 + tx + 16 * r;
            if (n < NLAB) out[(size_t)b * NLAB + n] = -acc[p][r];
        }
    }
}

// ---------------------------------------------------------------------------
extern "C" void kernel_launch(void* const* d_in, const int* in_sizes, int n_in,
                              void* d_out, int out_size, void* d_ws, size_t ws_size,
                              hipStream_t stream)
{
    const float* vfs = (const float*)d_in[0];   // [512,4096]
    const float* W1  = (const float*)d_in[1];   // [4096,2048]
    const float* b1  = (const float*)d_in[2];   // [2048]
    const float* W2  = (const float*)d_in[3];   // [2048,300]
    const float* b2  = (const float*)d_in[4];   // [300]
    const float* G   = (const float*)d_in[5];   // [2000,300]

    float* out    = (float*)d_out;
    float* scores = out;                        // [512*2000]
    float* E      = out + (size_t)B_SZ * NLAB;  // [512*300]

    // workspace layout (bytes): total ~46.4 MB
    char* ws = (char*)d_ws;
    unsigned short* Xb  = (unsigned short*)(ws);             //  4 MB   [512][4096]
    unsigned short* W1T = (unsigned short*)(ws + 4194304);   // 16 MB   [2048][4096]
    unsigned short* W2T = (unsigned short*)(ws + 20971520);  // 1.25 MB [320][2048]
    unsigned short* Hb  = (unsigned short*)(ws + 22282240);  //  2 MB   [512][2048]
    float*          Hpart = (float*)(ws + 24379392);         // 16 MB   [4][512][2048]
    float*          Epart = (float*)(ws + 41156608);         // 5.25 MB [8][512][320]

    prep_kernel<<<3232, 256, 0, stream>>>(vfs, Xb, W1, W1T, W2, W2T);

    // GEMM1: [512,2048] = Xb[512,4096] @ W1T^T, split-K 4 -> 1024 blocks
    gemm_bf16_kernel<VFD, VFD, HIDD, VFD / G1_SPLIT>
        <<<dim3(32, 8, G1_SPLIT), 256, 0, stream>>>(Xb, W1T, Hpart, B_SZ);
    reduce_h_kernel<<<1024, 256, 0, stream>>>(Hpart, b1, Hb);

    // GEMM2: [512,320] = Hb[512,2048] @ W2T^T, split-K 8 -> 320 blocks
    gemm_bf16_kernel<HIDD, HIDD, NPAD, HIDD / G2_SPLIT>
        <<<dim3(5, 8, G2_SPLIT), 256, 0, stream>>>(Hb, W2T, Epart, B_SZ);
    reduce_e_kernel<<<600, 256, 0, stream>>>(Epart, b2, E);

    scores_kernel<<<dim3(32, 16), 256, 0, stream>>>(E, G, scores);
}